// Round 7
// baseline (970.349 us; speedup 1.0000x reference)
//
#include <hip/hip_runtime.h>

constexpr float kEps = 1e-5f;

typedef float f2v __attribute__((ext_vector_type(2)));

__device__ __forceinline__ unsigned short f2bf(float x) {
  unsigned int u = __float_as_uint(x);
  unsigned int r = (u + 0x7fffu + ((u >> 16) & 1u)) >> 16;
  return (unsigned short)r;
}
__device__ __forceinline__ float bflo(unsigned int u) { return __uint_as_float(u << 16); }
__device__ __forceinline__ float bfhi(unsigned int u) { return __uint_as_float(u & 0xffff0000u); }
__device__ __forceinline__ unsigned int packbf(float a, float b) {
  return (unsigned int)f2bf(a) | ((unsigned int)f2bf(b) << 16);
}
__device__ __forceinline__ f2v fma2(f2v a, f2v b, f2v c) { return __builtin_elementwise_fma(a, b, c); }
__device__ __forceinline__ f2v splat2(float x) { f2v r; r.x = x; r.y = x; return r; }
__device__ __forceinline__ f2v unpk(unsigned int u) { f2v r; r.x = bflo(u); r.y = bfhi(u); return r; }
__device__ __forceinline__ f2v min2(f2v a, f2v b) { return __builtin_elementwise_min(a, b); }
__device__ __forceinline__ f2v max2(f2v a, f2v b) { return __builtin_elementwise_max(a, b); }

// ---------------- setup kernels ----------------

__global__ void zero_kernel(int* __restrict__ a, int* __restrict__ b,
                            float* __restrict__ bnb, int n) {
  int i = blockIdx.x * blockDim.x + threadIdx.x;
  if (i < n) { a[i] = 0; b[i] = 0; }
  if (i < 128) bnb[i] = 0.f;
}

__global__ void hist_kernel(const int* __restrict__ dst, int* __restrict__ deg, int E) {
  int e = blockIdx.x * blockDim.x + threadIdx.x;
  if (e < E) atomicAdd(&deg[dst[e]], 1);
}

__global__ void scan1_kernel(const int* __restrict__ deg, int* __restrict__ off,
                             int* __restrict__ part, int N) {
  __shared__ int sm[1024];
  int i = blockIdx.x * 1024 + threadIdx.x;
  int v = (i < N) ? deg[i] : 0;
  sm[threadIdx.x] = v;
  __syncthreads();
  for (int o = 1; o < 1024; o <<= 1) {
    int t = (threadIdx.x >= o) ? sm[threadIdx.x - o] : 0;
    __syncthreads();
    sm[threadIdx.x] += t;
    __syncthreads();
  }
  if (i < N) off[i] = sm[threadIdx.x] - v;   // exclusive
  if (threadIdx.x == 1023) part[blockIdx.x] = sm[1023];
}

__global__ void scan2_kernel(int* __restrict__ part, int* __restrict__ off, int nb, int N) {
  if (threadIdx.x == 0) {
    int run = 0;
    for (int b = 0; b < nb; b++) { int p = part[b]; part[b] = run; run += p; }
    off[N] = run;
  }
}

__global__ void scan3_kernel(int* __restrict__ off, const int* __restrict__ part, int N) {
  int i = blockIdx.x * 1024 + threadIdx.x;
  if (i < N) off[i] += part[blockIdx.x];
}

// CSR fill: scatter src/ew + bf16-packed eattr into slot order (edge order within
// node = atomic arrival order; perturbs fp reduction order at ulp level only)
__global__ void fill_kernel(const int* __restrict__ src, const int* __restrict__ dst,
                            const float* __restrict__ ew, const float4* __restrict__ eattr4,
                            const int* __restrict__ off, int* __restrict__ cnt,
                            int* __restrict__ srcs, float* __restrict__ ews,
                            uint4* __restrict__ egp, int E) {
  int e = blockIdx.x * blockDim.x + threadIdx.x;
  if (e < E) {
    int d = dst[e];
    int slot = off[d] + atomicAdd(&cnt[d], 1);
    srcs[slot] = src[e];
    ews[slot] = ew[e];
    float4 a = eattr4[e * 4 + 0], b = eattr4[e * 4 + 1];
    float4 c = eattr4[e * 4 + 2], q = eattr4[e * 4 + 3];
    uint4 u0, u1;
    u0.x = packbf(a.x, a.y); u0.y = packbf(a.z, a.w);
    u0.z = packbf(b.x, b.y); u0.w = packbf(b.z, b.w);
    u1.x = packbf(c.x, c.y); u1.y = packbf(c.z, c.w);
    u1.z = packbf(q.x, q.y); u1.w = packbf(q.z, q.w);
    egp[(size_t)slot * 2 + 0] = u0;
    egp[(size_t)slot * 2 + 1] = u1;
  }
}

__global__ void adl_kernel(const int* __restrict__ deg, float* __restrict__ adl, int N) {
  __shared__ float sm[1024];
  float s = 0.f;
  for (int n = threadIdx.x; n < N; n += 1024) s += logf((float)deg[n] + 1.f);
  sm[threadIdx.x] = s;
  __syncthreads();
  for (int o = 512; o > 0; o >>= 1) {
    if (threadIdx.x < o) sm[threadIdx.x] += sm[threadIdx.x + o];
    __syncthreads();
  }
  if (threadIdx.x == 0) adl[0] = sm[0];   // sum of log(deg+1); consumers divide by N
}

// h0 = x @ node_W + node_b   (x: [N,128], W: [128,32])
__global__ void node_emb_kernel(const float* __restrict__ x, const float* __restrict__ W,
                                const float* __restrict__ b, float* __restrict__ h, int N) {
  int n = blockIdx.x * 8 + (threadIdx.x >> 5);
  int j = threadIdx.x & 31;
  if (n >= N) return;
  float acc = b[j];
  const float4* x4 = (const float4*)(x + (size_t)n * 128);
#pragma unroll
  for (int q = 0; q < 32; q++) {
    float4 v = x4[q];
    acc += v.x * W[(4 * q + 0) * 32 + j];
    acc += v.y * W[(4 * q + 1) * 32 + j];
    acc += v.z * W[(4 * q + 2) * 32 + j];
    acc += v.w * W[(4 * q + 3) * 32 + j];
  }
  h[n * 32 + j] = acc;
}

// Fold edge path: Wf[l,t] = (edge_W @ enc_W[l]) @ pre_W[l,t,64:96,:]  (16x32)
__global__ void fuse_kernel(const float* __restrict__ edge_W, const float* __restrict__ edge_b,
                            const float* __restrict__ enc_W, const float* __restrict__ enc_b,
                            const float* __restrict__ pre_W, const float* __restrict__ pre_b,
                            float* __restrict__ Wf, float* __restrict__ bf) {
  __shared__ float tW[2][16][32];
  __shared__ float tb[2][32];
  int tid = threadIdx.x;
  for (int i = tid; i < 1024; i += 256) {
    int l = i >> 9, r = (i >> 5) & 15, c = i & 31;
    float s = 0.f;
    for (int k = 0; k < 32; k++) s += edge_W[r * 32 + k] * enc_W[(l * 32 + k) * 32 + c];
    tW[l][r][c] = s;
  }
  for (int i = tid; i < 64; i += 256) {
    int l = i >> 5, c = i & 31;
    float s = enc_b[l * 32 + c];
    for (int k = 0; k < 32; k++) s += edge_b[k] * enc_W[(l * 32 + k) * 32 + c];
    tb[l][c] = s;
  }
  __syncthreads();
  for (int i = tid; i < 4096; i += 256) {
    int l = i >> 11, t = (i >> 9) & 3, r = (i >> 5) & 15, c = i & 31;
    float s = 0.f;
    for (int k = 0; k < 32; k++) s += tW[l][r][k] * pre_W[((l * 4 + t) * 96 + 64 + k) * 32 + c];
    Wf[i] = s;
  }
  for (int i = tid; i < 256; i += 256) {
    int l = i >> 7, t = (i >> 5) & 3, c = i & 31;
    float s = pre_b[(l * 4 + t) * 32 + c];
    for (int k = 0; k < 32; k++) s += tb[l][k] * pre_W[((l * 4 + t) * 96 + 64 + k) * 32 + c];
    bf[i] = s;
  }
}

// ---------------- per-layer: node pre-projection ----------------
__global__ __launch_bounds__(256) void prep_kernel(
    const float* __restrict__ h, const float* __restrict__ preW,
    const float* __restrict__ bfv, unsigned short* __restrict__ qB,
    unsigned short* __restrict__ AB, int N) {
  __shared__ float hs[16][32];
  int tid = threadIdx.x;
  int c = tid & 127, half = tid >> 7;
  int t = c >> 5, g = c & 31;
  float ws[32], wd[32];
  {
    const float* pS = preW + (t * 96 + 32) * 32 + g;
    const float* pD = preW + (t * 96) * 32 + g;
#pragma unroll
    for (int k = 0; k < 32; k++) { ws[k] = pS[k * 32]; wd[k] = pD[k * 32]; }
  }
  float bc = bfv[c];
  int base = blockIdx.x * 16;
  for (int i = tid; i < 512; i += 256) {
    int nn = i >> 5;
    hs[nn][i & 31] = (base + nn < N) ? h[(size_t)(base + nn) * 32 + (i & 31)] : 0.f;
  }
  __syncthreads();
#pragma unroll
  for (int nn = 0; nn < 8; ++nn) {
    int nl = half + 2 * nn;
    int n = base + nl;
    if (n >= N) continue;
    float qa = 0.f, Aa = bc;
#pragma unroll
    for (int k = 0; k < 32; k++) {
      float hk = hs[nl][k];
      qa = fmaf(hk, ws[k], qa);
      Aa = fmaf(hk, wd[k], Aa);
    }
    qB[(size_t)n * 128 + c] = f2bf(qa);
    AB[(size_t)n * 128 + c] = f2bf(Aa);
  }
}

// ---------------- fused BN-apply + next-layer pre-projection ----------------
__global__ __launch_bounds__(256) void bnprep_kernel(
    const float* __restrict__ pre, const float* __restrict__ bnv,
    const float* __restrict__ gamma, const float* __restrict__ beta,
    const float* __restrict__ preW, const float* __restrict__ bfv,
    float* __restrict__ h, unsigned short* __restrict__ qB,
    unsigned short* __restrict__ AB, int N) {
  __shared__ float hs[16][32];
  int tid = threadIdx.x;
  int base = blockIdx.x * 16;
  float invN = 1.f / (float)N;
  for (int idx = tid; idx < 512; idx += 256) {
    int nn = idx >> 5, j = idx & 31;
    int n = base + nn;
    float v = 0.f;
    if (n < N) {
      float mu = bnv[j] * invN;
      float var = bnv[32 + j] * invN - mu * mu;
      float is = rsqrtf(var + kEps);
      v = fmaxf((pre[(size_t)n * 32 + j] - mu) * is * gamma[j] + beta[j], 0.f);
      h[(size_t)n * 32 + j] = v;
    }
    hs[nn][j] = v;
  }
  int c = tid & 127, half = tid >> 7;
  int t = c >> 5, g = c & 31;
  float ws[32], wd[32];
  {
    const float* pS = preW + (t * 96 + 32) * 32 + g;
    const float* pD = preW + (t * 96) * 32 + g;
#pragma unroll
    for (int k = 0; k < 32; k++) { ws[k] = pS[k * 32]; wd[k] = pD[k * 32]; }
  }
  float bc = bfv[c];
  __syncthreads();
#pragma unroll
  for (int nn = 0; nn < 8; ++nn) {
    int nl = half + 2 * nn;
    int n = base + nl;
    if (n >= N) continue;
    float qa = 0.f, Aa = bc;
#pragma unroll
    for (int k = 0; k < 32; k++) {
      float hk = hs[nl][k];
      qa = fmaf(hk, ws[k], qa);
      Aa = fmaf(hk, wd[k], Aa);
    }
    qB[(size_t)n * 128 + c] = f2bf(qa);
    AB[(size_t)n * 128 + c] = f2bf(Aa);
  }
}

// ---------------- per-layer: streaming edge-feature fold (GEMM) ----------------
// ef[slot][128] = eattr[slot][16] @ Wf ; 2 slots per wave, no gathers.
#define FOLDP(F, UA, UB)                                                       \
  { f2v p;                                                                     \
    p = unpk(UA.x); F = fma2(splat2(p.x), wf[0], F);  F = fma2(splat2(p.y), wf[1], F);  \
    p = unpk(UA.y); F = fma2(splat2(p.x), wf[2], F);  F = fma2(splat2(p.y), wf[3], F);  \
    p = unpk(UA.z); F = fma2(splat2(p.x), wf[4], F);  F = fma2(splat2(p.y), wf[5], F);  \
    p = unpk(UA.w); F = fma2(splat2(p.x), wf[6], F);  F = fma2(splat2(p.y), wf[7], F);  \
    p = unpk(UB.x); F = fma2(splat2(p.x), wf[8], F);  F = fma2(splat2(p.y), wf[9], F);  \
    p = unpk(UB.y); F = fma2(splat2(p.x), wf[10], F); F = fma2(splat2(p.y), wf[11], F); \
    p = unpk(UB.z); F = fma2(splat2(p.x), wf[12], F); F = fma2(splat2(p.y), wf[13], F); \
    p = unpk(UB.w); F = fma2(splat2(p.x), wf[14], F); F = fma2(splat2(p.y), wf[15], F); }

__global__ __launch_bounds__(256, 8) void efold_kernel(
    const uint4* __restrict__ egp, const float* __restrict__ Wf,
    unsigned int* __restrict__ eattrF, const int* __restrict__ coff,
    int n0, int n1, int bound) {
  int lane = threadIdx.x & 63;
  int wv = (blockIdx.x * blockDim.x + threadIdx.x) >> 6;
  int s0 = coff[n0], s1 = coff[n1];
  int base = s0 + wv * 2;
  if (base >= s1) return;
  int t = lane >> 4, g0 = (2 * lane) & 31;
  f2v wf[16];
  {
    const float* p = Wf + t * 512 + g0;
#pragma unroll
    for (int k = 0; k < 16; k++) { f2v r; r.x = p[k * 32]; r.y = p[k * 32 + 1]; wf[k] = r; }
  }
  uint4 ua = egp[(size_t)base * 2], ub = egp[(size_t)base * 2 + 1];
  bool has1 = (base + 1 < s1);
  uint4 uc, ud;
  if (has1) { uc = egp[(size_t)(base + 1) * 2]; ud = egp[(size_t)(base + 1) * 2 + 1]; }
  f2v f0 = splat2(0.f);
  FOLDP(f0, ua, ub)
  int idx0 = base - s0;
  if (idx0 < bound) eattrF[(size_t)idx0 * 64 + lane] = packbf(f0.x, f0.y);
  if (has1) {
    f2v f1 = splat2(0.f);
    FOLDP(f1, uc, ud)
    int idx1 = idx0 + 1;
    if (idx1 < bound) eattrF[(size_t)idx1 * 64 + lane] = packbf(f1.x, f1.y);
  }
}

// ---------------- per-layer: lightweight gather aggregation ----------------
#define STAT2(V)                                                \
  sum = sum + V; sq = fma2(V, V, sq); mn = min2(mn, V); mx = max2(mx, V);

__global__ __launch_bounds__(256, 8) void agg5_kernel(
    const unsigned int* __restrict__ qB, const unsigned int* __restrict__ AB,
    const int* __restrict__ coff, const int* __restrict__ srcs,
    const float* __restrict__ ews, const unsigned int* __restrict__ eattrF,
    unsigned int* __restrict__ stats, int n0, int n1, int bound) {
  int lane = threadIdx.x & 63;
  int n = n0 + ((blockIdx.x * blockDim.x + threadIdx.x) >> 6);
  if (n >= n1) return;
  int s0c = coff[n0];
  f2v a = unpk(AB[(size_t)n * 64 + lane]);
  int beg = coff[n], end = coff[n + 1];
  int dg = end - beg;
  f2v sum = splat2(0.f), sq = splat2(0.f);
  f2v mn = splat2(1e30f), mx = splat2(-1e30f);
  int bm = bound - 1;
  int i = beg;
  int sA0 = 0, sA1 = 0, sA2 = 0, sA3 = 0, sA4 = 0, sA5 = 0, sA6 = 0, sA7 = 0;
  if (i + 8 <= end) {
    sA0 = srcs[i];     sA1 = srcs[i + 1]; sA2 = srcs[i + 2]; sA3 = srcs[i + 3];
    sA4 = srcs[i + 4]; sA5 = srcs[i + 5]; sA6 = srcs[i + 6]; sA7 = srcs[i + 7];
  }
  for (; i + 8 <= end;) {
    // load cluster: 8 q-gathers + 8 ef stream + 8 w stream
    unsigned int q0 = qB[(size_t)sA0 * 64 + lane];
    unsigned int q1 = qB[(size_t)sA1 * 64 + lane];
    unsigned int q2 = qB[(size_t)sA2 * 64 + lane];
    unsigned int q3 = qB[(size_t)sA3 * 64 + lane];
    unsigned int q4 = qB[(size_t)sA4 * 64 + lane];
    unsigned int q5 = qB[(size_t)sA5 * 64 + lane];
    unsigned int q6 = qB[(size_t)sA6 * 64 + lane];
    unsigned int q7 = qB[(size_t)sA7 * 64 + lane];
    int ib = i - s0c;
    unsigned int f0 = eattrF[(size_t)min(ib + 0, bm) * 64 + lane];
    unsigned int f1 = eattrF[(size_t)min(ib + 1, bm) * 64 + lane];
    unsigned int f2_ = eattrF[(size_t)min(ib + 2, bm) * 64 + lane];
    unsigned int f3 = eattrF[(size_t)min(ib + 3, bm) * 64 + lane];
    unsigned int f4 = eattrF[(size_t)min(ib + 4, bm) * 64 + lane];
    unsigned int f5 = eattrF[(size_t)min(ib + 5, bm) * 64 + lane];
    unsigned int f6 = eattrF[(size_t)min(ib + 6, bm) * 64 + lane];
    unsigned int f7 = eattrF[(size_t)min(ib + 7, bm) * 64 + lane];
    float w0 = ews[i],     w1 = ews[i + 1], w2 = ews[i + 2], w3 = ews[i + 3];
    float w4 = ews[i + 4], w5 = ews[i + 5], w6 = ews[i + 6], w7 = ews[i + 7];
    i += 8;
    if (i + 8 <= end) {  // prefetch next batch indices
      sA0 = srcs[i];     sA1 = srcs[i + 1]; sA2 = srcs[i + 2]; sA3 = srcs[i + 3];
      sA4 = srcs[i + 4]; sA5 = srcs[i + 5]; sA6 = srcs[i + 6]; sA7 = srcs[i + 7];
    }
    f2v v;
    v = (a + unpk(q0) + unpk(f0)) * splat2(w0); STAT2(v)
    v = (a + unpk(q1) + unpk(f1)) * splat2(w1); STAT2(v)
    v = (a + unpk(q2) + unpk(f2_)) * splat2(w2); STAT2(v)
    v = (a + unpk(q3) + unpk(f3)) * splat2(w3); STAT2(v)
    v = (a + unpk(q4) + unpk(f4)) * splat2(w4); STAT2(v)
    v = (a + unpk(q5) + unpk(f5)) * splat2(w5); STAT2(v)
    v = (a + unpk(q6) + unpk(f6)) * splat2(w6); STAT2(v)
    v = (a + unpk(q7) + unpk(f7)) * splat2(w7); STAT2(v)
  }
  for (; i < end; ++i) {
    int s = srcs[i];
    unsigned int q = qB[(size_t)s * 64 + lane];
    unsigned int f = eattrF[(size_t)min(i - s0c, bm) * 64 + lane];
    float w = ews[i];
    f2v v = (a + unpk(q) + unpk(f)) * splat2(w);
    STAT2(v)
  }
  if (dg == 0) { mn = splat2(0.f); mx = splat2(0.f); }
  float inv = 1.f / (float)(dg > 0 ? dg : 1);
  f2v mean = sum * splat2(inv);
  f2v var = sq * splat2(inv) - mean * mean;
  float sd0 = sqrtf(fmaxf(var.x, 0.f) + kEps);
  float sd1 = sqrtf(fmaxf(var.y, 0.f) + kEps);
  unsigned int* sp = stats + (size_t)n * 256;
  sp[0 * 64 + lane] = packbf(mean.x, mean.y);
  sp[1 * 64 + lane] = packbf(mn.x, mn.y);
  sp[2 * 64 + lane] = packbf(mx.x, mx.y);
  sp[3 * 64 + lane] = packbf(sd0, sd1);
}

// ---------------- per-layer: post_nn + lin + BN partials ----------------
__global__ __launch_bounds__(256) void post_kernel(
    const float* __restrict__ h, const unsigned int* __restrict__ stats,
    const int* __restrict__ coff, const float* __restrict__ adl,
    const float* __restrict__ postW, const float* __restrict__ postB,
    const float* __restrict__ linW, const float* __restrict__ linB,
    float* __restrict__ pre, float* __restrict__ bn, int N) {
  __shared__ unsigned int pwp[208 * 32];   // rows paired (2r,2r+1): 26 KB
  __shared__ unsigned int stu[4][256];     // per-wave raw stats rows: 4 KB
  __shared__ float red[8][32];             // BN partial reduce: 1 KB
  int tid = threadIdx.x;
  for (int i = tid; i < 6656; i += 256) {
    int r = i >> 5, cc = i & 31, tP = cc >> 3, gq = cc & 7;
    float lo = postW[tP * 3328 + (2 * r) * 8 + gq];
    float hi = postW[tP * 3328 + (2 * r + 1) * 8 + gq];
    pwp[i] = packbf(lo, hi);
  }
  __syncthreads();

  int wave = tid >> 6, lane = tid & 63;
  int c = lane & 31, hh = lane >> 5;
  int tP = c >> 3;
  float adN = adl[0];
  float bs = 0.f, bq = 0.f;

  for (int n = blockIdx.x * 4 + wave; n < N; n += gridDim.x * 4) {
    {
      uint4 su = ((const uint4*)stats)[(size_t)n * 64 + lane];
      ((uint4*)stu[wave])[lane] = su;   // per-wave region: no block barrier needed
    }
    int dg = coff[n + 1] - coff[n];
    float degc = (float)(dg > 0 ? dg : 1);
    float ad = adN / (float)N;
    float ld = logf(degc + 1.f);
    float amp = ld / ad, att = ad / ld;

    float acc = (hh == 0) ? postB[tP * 8 + (c & 7)] : 0.f;
    const float4* h4 = (const float4*)(h + (size_t)n * 32);
#pragma unroll
    for (int q4 = 0; q4 < 4; q4++) {
      float4 hv = h4[hh * 4 + q4];
      int r0 = hh * 8 + q4 * 2;
      unsigned int u0 = pwp[r0 * 32 + c], u1 = pwp[(r0 + 1) * 32 + c];
      acc = fmaf(hv.x, bflo(u0), acc);
      acc = fmaf(hv.y, bfhi(u0), acc);
      acc = fmaf(hv.z, bflo(u1), acc);
      acc = fmaf(hv.w, bfhi(u1), acc);
    }
#pragma unroll 8
    for (int jj = 0; jj < 32; jj++) {
      int sIdx = hh * 2 + (jj >> 4);
      unsigned int sv = stu[wave][sIdx * 64 + tP * 16 + (jj & 15)];
      float v0 = bflo(sv), v1 = bfhi(sv);
      int rm = 16 + hh * 32 + jj, ra = 80 + hh * 32 + jj, rt = 144 + hh * 32 + jj;
      unsigned int um = pwp[rm * 32 + c];
      unsigned int ua = pwp[ra * 32 + c];
      unsigned int ut = pwp[rt * 32 + c];
      float w0 = bflo(um); w0 = fmaf(amp, bflo(ua), w0); w0 = fmaf(att, bflo(ut), w0);
      float w1 = bfhi(um); w1 = fmaf(amp, bfhi(ua), w1); w1 = fmaf(att, bfhi(ut), w1);
      acc = fmaf(v0, w0, acc);
      acc = fmaf(v1, w1, acc);
    }
    acc += __shfl_xor(acc, 32);
    float o = linB[c];
#pragma unroll
    for (int k = 0; k < 32; k++) {
      float a = __shfl(acc, k);
      o = fmaf(a, linW[k * 32 + c], o);
    }
    if (lane < 32) {
      pre[(size_t)n * 32 + c] = o;
      bs += o;
      bq = fmaf(o, o, bq);
    }
  }

  __syncthreads();
  if (lane < 32) {
    red[wave * 2 + 0][c] = bs;
    red[wave * 2 + 1][c] = bq;
  }
  __syncthreads();
  if (tid < 64) {
    int which = tid >> 5, cc = tid & 31;
    float s = red[0 * 2 + which][cc] + red[1 * 2 + which][cc] +
              red[2 * 2 + which][cc] + red[3 * 2 + which][cc];
    atomicAdd(&bn[which * 32 + cc], s);
  }
}

// ---------------- fused BN-apply + pooling, then MLP ----------------

__device__ __forceinline__ int lower_bound_dev(const int* a, int n, int key) {
  int lo = 0, hi = n;
  while (lo < hi) {
    int m = (lo + hi) >> 1;
    if (a[m] < key) lo = m + 1; else hi = m;
  }
  return lo;
}

__global__ void pool2_kernel(const float* __restrict__ pre, const float* __restrict__ bnv,
                             const float* __restrict__ gamma, const float* __restrict__ beta,
                             const int* __restrict__ batch, float* __restrict__ gp, int N) {
  int gi = blockIdx.x;  // 64 graphs
  int lo = lower_bound_dev(batch, N, gi);
  int hi = lower_bound_dev(batch, N, gi + 1);
  __shared__ float part[8][32];
  int j = threadIdx.x & 31, ch = threadIdx.x >> 5;
  float invN = 1.f / (float)N;
  float mu = bnv[j] * invN;
  float var = bnv[32 + j] * invN - mu * mu;
  float is = rsqrtf(var + kEps);
  float gm = gamma[j], bt = beta[j];
  float s = 0.f;
  for (int n = lo + ch; n < hi; n += 8)
    s += fmaxf((pre[(size_t)n * 32 + j] - mu) * is * gm + bt, 0.f);
  part[ch][j] = s;
  __syncthreads();
  if (threadIdx.x < 32) {
    float t = 0.f;
    for (int c2 = 0; c2 < 8; c2++) t += part[c2][j];
    gp[gi * 32 + j] = t;
  }
}

__global__ void mlp_kernel(const float* __restrict__ gp,
                           const float* __restrict__ W1, const float* __restrict__ b1,
                           const float* __restrict__ W2, const float* __restrict__ b2,
                           const float* __restrict__ W3, const float* __restrict__ b3,
                           float* __restrict__ out) {
  __shared__ float g1[64 * 32];
  __shared__ float g2[64 * 16];
  int tid = threadIdx.x;  // 256
  for (int i = tid; i < 2048; i += 256) {
    int r = i >> 5, c = i & 31;
    float s = b1[c];
    for (int k = 0; k < 32; k++) s += gp[r * 32 + k] * W1[k * 32 + c];
    g1[i] = fmaxf(s, 0.f);
  }
  __syncthreads();
  for (int i = tid; i < 1024; i += 256) {
    int r = i >> 4, c = i & 15;
    float s = b2[c];
    for (int k = 0; k < 32; k++) s += g1[r * 32 + k] * W2[k * 16 + c];
    g2[i] = fmaxf(s, 0.f);
  }
  __syncthreads();
  if (tid < 64) {
    float s = b3[0];
    for (int k = 0; k < 16; k++) s += g2[tid * 16 + k] * W3[k];
    out[tid] = s;
  }
}

// ---------------- launch ----------------

extern "C" void kernel_launch(void* const* d_in, const int* in_sizes, int n_in,
                              void* d_out, int out_size, void* d_ws, size_t ws_size,
                              hipStream_t stream) {
  (void)n_in; (void)out_size;
  const float* x     = (const float*)d_in[0];
  const float* eattr = (const float*)d_in[1];
  const float* ew    = (const float*)d_in[2];
  const int*   eidx  = (const int*)d_in[3];
  const int*   batch = (const int*)d_in[4];
  const float* nodeW = (const float*)d_in[5];
  const float* nodeB = (const float*)d_in[6];
  const float* edgeW = (const float*)d_in[7];
  const float* edgeB = (const float*)d_in[8];
  const float* encW  = (const float*)d_in[9];
  const float* encB  = (const float*)d_in[10];
  const float* preW  = (const float*)d_in[11];
  const float* preB  = (const float*)d_in[12];
  const float* postW = (const float*)d_in[13];
  const float* postB = (const float*)d_in[14];
  const float* linW  = (const float*)d_in[15];
  const float* linB  = (const float*)d_in[16];
  const float* bnG   = (const float*)d_in[17];
  const float* bnB   = (const float*)d_in[18];
  const float* W1    = (const float*)d_in[19];
  const float* b1    = (const float*)d_in[20];
  const float* W2    = (const float*)d_in[21];
  const float* b2    = (const float*)d_in[22];
  const float* W3    = (const float*)d_in[23];
  const float* b3    = (const float*)d_in[24];
  float* out = (float*)d_out;

  int N = in_sizes[0] / 128;
  int E = in_sizes[2];
  const int* srcp = eidx;
  const int* dstp = eidx + E;

  char* wsb = (char*)d_ws;
  size_t woff = 0;
  auto alloc = [&](size_t bytes) -> void* {
    void* p = (void*)(wsb + woff);
    woff += (bytes + 255) & ~(size_t)255;
    return p;
  };
  int* deg   = (int*)alloc((size_t)N * 4);
  int* cnt   = (int*)alloc((size_t)N * 4);
  int* coff  = (int*)alloc((size_t)(N + 1) * 4);
  int* part  = (int*)alloc(64 * 4);
  int* srcs  = (int*)alloc((size_t)E * 4);
  float* ews = (float*)alloc((size_t)E * 4);
  unsigned int* egp = (unsigned int*)alloc((size_t)E * 32);   // bf16-packed eattr, slot order
  float* h    = (float*)alloc((size_t)N * 32 * 4);
  float* pre  = (float*)alloc((size_t)N * 32 * 4);
  float* adl  = (float*)alloc(256);
  float* bnbuf = (float*)alloc(2 * 64 * 4);
  float* gp   = (float*)alloc(64 * 32 * 4);
  float* WfB  = (float*)alloc(2 * 4 * 16 * 32 * 4);
  float* bfB  = (float*)alloc(2 * 4 * 32 * 4);
  unsigned short* qB  = (unsigned short*)alloc((size_t)N * 128 * 2);
  unsigned short* AB  = (unsigned short*)alloc((size_t)N * 128 * 2);
  unsigned int* stats = (unsigned int*)alloc((size_t)N * 256 * 4);

  // adaptive eattrF chunking based on remaining workspace
  size_t fixed = woff;
  size_t avail = (ws_size > fixed + (1u << 20)) ? (ws_size - fixed - (1u << 20)) : 0;
  size_t cap_slots = avail / 256;
  int k = 1;
  if (cap_slots < (size_t)E) {
    for (k = 2; k <= 64; ++k) {
      size_t b = (size_t)E / k + (size_t)E / (k * 16) + 4096;
      if (b <= cap_slots) break;
    }
  }
  int bound = (k == 1) ? E : (int)((size_t)E / k + (size_t)E / (k * 16) + 4096);
  unsigned int* eattrF = (unsigned int*)alloc((size_t)bound * 256);
  int ncn = (N + k - 1) / k;
  int grid_e = (bound + 7) / 8;    // 2 slots/wave, 4 waves/block
  int grid_a = (ncn + 3) / 4;      // 1 node/wave

  int nb = (N + 1023) / 1024;
  zero_kernel<<<(N + 255) / 256, 256, 0, stream>>>(deg, cnt, bnbuf, N);
  hist_kernel<<<(E + 255) / 256, 256, 0, stream>>>(dstp, deg, E);
  scan1_kernel<<<nb, 1024, 0, stream>>>(deg, coff, part, N);
  scan2_kernel<<<1, 64, 0, stream>>>(part, coff, nb, N);
  scan3_kernel<<<nb, 1024, 0, stream>>>(coff, part, N);
  fill_kernel<<<(E + 255) / 256, 256, 0, stream>>>(srcp, dstp, ew, (const float4*)eattr,
                                                   coff, cnt, srcs, ews, (uint4*)egp, E);
  adl_kernel<<<1, 1024, 0, stream>>>(deg, adl, N);
  node_emb_kernel<<<(N + 7) / 8, 256, 0, stream>>>(x, nodeW, nodeB, h, N);
  fuse_kernel<<<1, 256, 0, stream>>>(edgeW, edgeB, encW, encB, preW, preB, WfB, bfB);

  // layer 0
  prep_kernel<<<(N + 15) / 16, 256, 0, stream>>>(h, preW, bfB, qB, AB, N);
  for (int c = 0; c < k; ++c) {
    int n0 = c * ncn, n1 = (n0 + ncn < N) ? n0 + ncn : N;
    if (n0 >= n1) break;
    efold_kernel<<<grid_e, 256, 0, stream>>>((const uint4*)egp, WfB, eattrF, coff, n0, n1, bound);
    agg5_kernel<<<grid_a, 256, 0, stream>>>(
        (const unsigned int*)qB, (const unsigned int*)AB, coff, srcs, ews,
        eattrF, stats, n0, n1, bound);
  }
  post_kernel<<<1280, 256, 0, stream>>>(
      h, stats, coff, adl, postW, postB, linW, linB, pre, bnbuf, N);
  // fused bn_apply(l0) + prep(l1)
  bnprep_kernel<<<(N + 15) / 16, 256, 0, stream>>>(
      pre, bnbuf, bnG, bnB, preW + 12288, bfB + 128, h, qB, AB, N);
  // layer 1
  for (int c = 0; c < k; ++c) {
    int n0 = c * ncn, n1 = (n0 + ncn < N) ? n0 + ncn : N;
    if (n0 >= n1) break;
    efold_kernel<<<grid_e, 256, 0, stream>>>((const uint4*)egp, WfB + 2048, eattrF, coff, n0, n1, bound);
    agg5_kernel<<<grid_a, 256, 0, stream>>>(
        (const unsigned int*)qB, (const unsigned int*)AB, coff, srcs, ews,
        eattrF, stats, n0, n1, bound);
  }
  post_kernel<<<1280, 256, 0, stream>>>(
      h, stats, coff, adl, postW + 13312, postB + 32, linW + 1024, linB + 32,
      pre, bnbuf + 64, N);
  // fused bn_apply(l1) + pooling
  pool2_kernel<<<64, 256, 0, stream>>>(pre, bnbuf + 64, bnG + 32, bnB + 32, batch, gp, N);
  mlp_kernel<<<1, 256, 0, stream>>>(gp, W1, b1, W2, b2, W3, b3, out);
}

// Round 8
// 480.237 us; speedup vs baseline: 2.0206x; 2.0206x over previous
//
#include <hip/hip_runtime.h>

constexpr float kEps = 1e-5f;

__device__ __forceinline__ unsigned short f2bf(float x) {
  unsigned int u = __float_as_uint(x);
  unsigned int r = (u + 0x7fffu + ((u >> 16) & 1u)) >> 16;
  return (unsigned short)r;
}
__device__ __forceinline__ float bflo(unsigned int u) { return __uint_as_float(u << 16); }
__device__ __forceinline__ float bfhi(unsigned int u) { return __uint_as_float(u & 0xffff0000u); }
__device__ __forceinline__ unsigned int packbf(float a, float b) {
  return (unsigned int)f2bf(a) | ((unsigned int)f2bf(b) << 16);
}

// ---------------- setup kernels ----------------

__global__ void zero_kernel(int* __restrict__ a, int* __restrict__ b,
                            float* __restrict__ bnb, int n) {
  int i = blockIdx.x * blockDim.x + threadIdx.x;
  if (i < n) { a[i] = 0; b[i] = 0; }
  if (i < 128) bnb[i] = 0.f;
}

__global__ void hist_kernel(const int* __restrict__ dst, int* __restrict__ deg, int E) {
  int e = blockIdx.x * blockDim.x + threadIdx.x;
  if (e < E) atomicAdd(&deg[dst[e]], 1);
}

__global__ void scan1_kernel(const int* __restrict__ deg, int* __restrict__ off,
                             int* __restrict__ part, int N) {
  __shared__ int sm[1024];
  int i = blockIdx.x * 1024 + threadIdx.x;
  int v = (i < N) ? deg[i] : 0;
  sm[threadIdx.x] = v;
  __syncthreads();
  for (int o = 1; o < 1024; o <<= 1) {
    int t = (threadIdx.x >= o) ? sm[threadIdx.x - o] : 0;
    __syncthreads();
    sm[threadIdx.x] += t;
    __syncthreads();
  }
  if (i < N) off[i] = sm[threadIdx.x] - v;   // exclusive
  if (threadIdx.x == 1023) part[blockIdx.x] = sm[1023];
}

__global__ void scan2_kernel(int* __restrict__ part, int* __restrict__ off, int nb, int N) {
  if (threadIdx.x == 0) {
    int run = 0;
    for (int b = 0; b < nb; b++) { int p = part[b]; part[b] = run; run += p; }
    off[N] = run;
  }
}

__global__ void scan3_kernel(int* __restrict__ off, const int* __restrict__ part, int N) {
  int i = blockIdx.x * 1024 + threadIdx.x;
  if (i < N) off[i] += part[blockIdx.x];
}

// CSR fill: scatter src/ew/eattr into slot order in one pass (edge order within
// node = atomic arrival order; perturbs fp reduction order at ulp level only)
__global__ void fill_kernel(const int* __restrict__ src, const int* __restrict__ dst,
                            const float* __restrict__ ew, const float4* __restrict__ eattr4,
                            const int* __restrict__ off, int* __restrict__ cnt,
                            int* __restrict__ srcs, float* __restrict__ ews,
                            float4* __restrict__ eattrg4, int E) {
  int e = blockIdx.x * blockDim.x + threadIdx.x;
  if (e < E) {
    int d = dst[e];
    int slot = off[d] + atomicAdd(&cnt[d], 1);
    srcs[slot] = src[e];
    ews[slot] = ew[e];
    float4 a = eattr4[e * 4 + 0], b = eattr4[e * 4 + 1];
    float4 c = eattr4[e * 4 + 2], q = eattr4[e * 4 + 3];
    eattrg4[(size_t)slot * 4 + 0] = a;
    eattrg4[(size_t)slot * 4 + 1] = b;
    eattrg4[(size_t)slot * 4 + 2] = c;
    eattrg4[(size_t)slot * 4 + 3] = q;
  }
}

__global__ void adl_kernel(const int* __restrict__ deg, float* __restrict__ adl, int N) {
  __shared__ float sm[1024];
  float s = 0.f;
  for (int n = threadIdx.x; n < N; n += 1024) s += logf((float)deg[n] + 1.f);
  sm[threadIdx.x] = s;
  __syncthreads();
  for (int o = 512; o > 0; o >>= 1) {
    if (threadIdx.x < o) sm[threadIdx.x] += sm[threadIdx.x + o];
    __syncthreads();
  }
  if (threadIdx.x == 0) adl[0] = sm[0];   // sum of log(deg+1); consumers divide by N
}

// h0 = x @ node_W + node_b   (x: [N,128], W: [128,32])
__global__ void node_emb_kernel(const float* __restrict__ x, const float* __restrict__ W,
                                const float* __restrict__ b, float* __restrict__ h, int N) {
  int n = blockIdx.x * 8 + (threadIdx.x >> 5);
  int j = threadIdx.x & 31;
  if (n >= N) return;
  float acc = b[j];
  const float4* x4 = (const float4*)(x + (size_t)n * 128);
#pragma unroll
  for (int q = 0; q < 32; q++) {
    float4 v = x4[q];
    acc += v.x * W[(4 * q + 0) * 32 + j];
    acc += v.y * W[(4 * q + 1) * 32 + j];
    acc += v.z * W[(4 * q + 2) * 32 + j];
    acc += v.w * W[(4 * q + 3) * 32 + j];
  }
  h[n * 32 + j] = acc;
}

// Fold edge path: Wf[l,t] = (edge_W @ enc_W[l]) @ pre_W[l,t,64:96,:]  (16x32)
__global__ void fuse_kernel(const float* __restrict__ edge_W, const float* __restrict__ edge_b,
                            const float* __restrict__ enc_W, const float* __restrict__ enc_b,
                            const float* __restrict__ pre_W, const float* __restrict__ pre_b,
                            float* __restrict__ Wf, float* __restrict__ bf) {
  __shared__ float tW[2][16][32];
  __shared__ float tb[2][32];
  int tid = threadIdx.x;
  for (int i = tid; i < 1024; i += 256) {
    int l = i >> 9, r = (i >> 5) & 15, c = i & 31;
    float s = 0.f;
    for (int k = 0; k < 32; k++) s += edge_W[r * 32 + k] * enc_W[(l * 32 + k) * 32 + c];
    tW[l][r][c] = s;
  }
  for (int i = tid; i < 64; i += 256) {
    int l = i >> 5, c = i & 31;
    float s = enc_b[l * 32 + c];
    for (int k = 0; k < 32; k++) s += edge_b[k] * enc_W[(l * 32 + k) * 32 + c];
    tb[l][c] = s;
  }
  __syncthreads();
  for (int i = tid; i < 4096; i += 256) {
    int l = i >> 11, t = (i >> 9) & 3, r = (i >> 5) & 15, c = i & 31;
    float s = 0.f;
    for (int k = 0; k < 32; k++) s += tW[l][r][k] * pre_W[((l * 4 + t) * 96 + 64 + k) * 32 + c];
    Wf[i] = s;
  }
  for (int i = tid; i < 256; i += 256) {
    int l = i >> 7, t = (i >> 5) & 3, c = i & 31;
    float s = pre_b[(l * 4 + t) * 32 + c];
    for (int k = 0; k < 32; k++) s += tb[l][k] * pre_W[((l * 4 + t) * 96 + 64 + k) * 32 + c];
    bf[i] = s;
  }
}

// ---------------- per-layer: node pre-projection ----------------
__global__ __launch_bounds__(256) void prep_kernel(
    const float* __restrict__ h, const float* __restrict__ preW,
    const float* __restrict__ bfv, unsigned short* __restrict__ qB,
    unsigned short* __restrict__ AB, int N) {
  __shared__ float hs[16][32];
  int tid = threadIdx.x;
  int c = tid & 127, half = tid >> 7;
  int t = c >> 5, g = c & 31;
  float ws[32], wd[32];
  {
    const float* pS = preW + (t * 96 + 32) * 32 + g;
    const float* pD = preW + (t * 96) * 32 + g;
#pragma unroll
    for (int k = 0; k < 32; k++) { ws[k] = pS[k * 32]; wd[k] = pD[k * 32]; }
  }
  float bc = bfv[c];
  int base = blockIdx.x * 16;
  for (int i = tid; i < 512; i += 256) {
    int nn = i >> 5;
    hs[nn][i & 31] = (base + nn < N) ? h[(size_t)(base + nn) * 32 + (i & 31)] : 0.f;
  }
  __syncthreads();
#pragma unroll
  for (int nn = 0; nn < 8; ++nn) {
    int nl = half + 2 * nn;
    int n = base + nl;
    if (n >= N) continue;
    float qa = 0.f, Aa = bc;
#pragma unroll
    for (int k = 0; k < 32; k++) {
      float hk = hs[nl][k];
      qa = fmaf(hk, ws[k], qa);
      Aa = fmaf(hk, wd[k], Aa);
    }
    qB[(size_t)n * 128 + c] = f2bf(qa);
    AB[(size_t)n * 128 + c] = f2bf(Aa);
  }
}

// ---------------- fused BN-apply + next-layer pre-projection ----------------
__global__ __launch_bounds__(256) void bnprep_kernel(
    const float* __restrict__ pre, const float* __restrict__ bnv,
    const float* __restrict__ gamma, const float* __restrict__ beta,
    const float* __restrict__ preW, const float* __restrict__ bfv,
    float* __restrict__ h, unsigned short* __restrict__ qB,
    unsigned short* __restrict__ AB, int N) {
  __shared__ float hs[16][32];
  int tid = threadIdx.x;
  int base = blockIdx.x * 16;
  float invN = 1.f / (float)N;
  for (int idx = tid; idx < 512; idx += 256) {
    int nn = idx >> 5, j = idx & 31;
    int n = base + nn;
    float v = 0.f;
    if (n < N) {
      float mu = bnv[j] * invN;
      float var = bnv[32 + j] * invN - mu * mu;
      float is = rsqrtf(var + kEps);
      v = fmaxf((pre[(size_t)n * 32 + j] - mu) * is * gamma[j] + beta[j], 0.f);
      h[(size_t)n * 32 + j] = v;
    }
    hs[nn][j] = v;
  }
  int c = tid & 127, half = tid >> 7;
  int t = c >> 5, g = c & 31;
  float ws[32], wd[32];
  {
    const float* pS = preW + (t * 96 + 32) * 32 + g;
    const float* pD = preW + (t * 96) * 32 + g;
#pragma unroll
    for (int k = 0; k < 32; k++) { ws[k] = pS[k * 32]; wd[k] = pD[k * 32]; }
  }
  float bc = bfv[c];
  __syncthreads();
#pragma unroll
  for (int nn = 0; nn < 8; ++nn) {
    int nl = half + 2 * nn;
    int n = base + nl;
    if (n >= N) continue;
    float qa = 0.f, Aa = bc;
#pragma unroll
    for (int k = 0; k < 32; k++) {
      float hk = hs[nl][k];
      qa = fmaf(hk, ws[k], qa);
      Aa = fmaf(hk, wd[k], Aa);
    }
    qB[(size_t)n * 128 + c] = f2bf(qa);
    AB[(size_t)n * 128 + c] = f2bf(Aa);
  }
}

// ---------------- per-layer: fused batched aggregation, 2 waves/node ----------------
#define FOLD8(F0, F1, VA, VB, O)                                           \
  F0 = fmaf(VA.x, wfa[O + 0], F0); F1 = fmaf(VA.x, wfb[O + 0], F1);        \
  F0 = fmaf(VA.y, wfa[O + 1], F0); F1 = fmaf(VA.y, wfb[O + 1], F1);        \
  F0 = fmaf(VA.z, wfa[O + 2], F0); F1 = fmaf(VA.z, wfb[O + 2], F1);        \
  F0 = fmaf(VA.w, wfa[O + 3], F0); F1 = fmaf(VA.w, wfb[O + 3], F1);        \
  F0 = fmaf(VB.x, wfa[O + 4], F0); F1 = fmaf(VB.x, wfb[O + 4], F1);        \
  F0 = fmaf(VB.y, wfa[O + 5], F0); F1 = fmaf(VB.y, wfb[O + 5], F1);        \
  F0 = fmaf(VB.z, wfa[O + 6], F0); F1 = fmaf(VB.z, wfb[O + 6], F1);        \
  F0 = fmaf(VB.w, wfa[O + 7], F0); F1 = fmaf(VB.w, wfb[O + 7], F1);

#define STATACC(V0, V1)                                                    \
  s0a += V0; sq0 = fmaf(V0, V0, sq0); mn0 = fminf(mn0, V0); mx0 = fmaxf(mx0, V0); \
  s1a += V1; sq1 = fmaf(V1, V1, sq1); mn1 = fminf(mn1, V1); mx1 = fmaxf(mx1, V1);

__global__ __launch_bounds__(256, 4) void agg6_kernel(
    const unsigned int* __restrict__ qB, const unsigned int* __restrict__ AB,
    const int* __restrict__ coff, const int* __restrict__ srcs,
    const float* __restrict__ ews, const float* __restrict__ eattrg,
    const float* __restrict__ Wf, unsigned int* __restrict__ stats, int N) {
  __shared__ float comb[2][64][8];   // half1 partials
  int tid = threadIdx.x, wave = tid >> 6, lane = tid & 63;
  int pairIdx = wave >> 1, half = wave & 1;
  int n = blockIdx.x * 2 + pairIdx;
  bool valid = (n < N);
  int t = lane >> 4, g0 = (2 * lane) & 31;
  float wfa[16], wfb[16];
  {
    const float* p = Wf + t * 512 + g0;
#pragma unroll
    for (int k = 0; k < 16; k++) { wfa[k] = p[k * 32]; wfb[k] = p[k * 32 + 1]; }
  }
  float a0 = 0.f, a1 = 0.f;
  int lo = 0, hi = 0, dg = 0;
  if (valid) {
    unsigned int au = AB[(size_t)n * 64 + lane];
    a0 = bflo(au); a1 = bfhi(au);
    int beg = coff[n], end = coff[n + 1];
    dg = end - beg;
    int mid = beg + ((dg + 1) >> 1);
    lo = half ? mid : beg;
    hi = half ? end : mid;
  }
  float s0a = 0.f, s1a = 0.f, sq0 = 0.f, sq1 = 0.f;
  float mn0 = 1e30f, mn1 = 1e30f, mx0 = -1e30f, mx1 = -1e30f;

  int i = lo;
  int sc0 = 0, sc1 = 0, sc2 = 0, sc3 = 0;
  if (i + 4 <= hi) { sc0 = srcs[i]; sc1 = srcs[i + 1]; sc2 = srcs[i + 2]; sc3 = srcs[i + 3]; }
  for (; i + 4 <= hi; i += 4) {
    unsigned int q0 = qB[(size_t)sc0 * 64 + lane];
    unsigned int q1 = qB[(size_t)sc1 * 64 + lane];
    unsigned int q2 = qB[(size_t)sc2 * 64 + lane];
    unsigned int q3 = qB[(size_t)sc3 * 64 + lane];
    float w0 = ews[i], w1 = ews[i + 1], w2 = ews[i + 2], w3 = ews[i + 3];
    const float4* ep = (const float4*)(eattrg + (size_t)i * 16);
    if (i + 8 <= hi) { sc0 = srcs[i + 4]; sc1 = srcs[i + 5]; sc2 = srcs[i + 6]; sc3 = srcs[i + 7]; }
    float f00 = 0.f, f10 = 0.f, f01 = 0.f, f11 = 0.f;
    float f02 = 0.f, f12 = 0.f, f03 = 0.f, f13 = 0.f;
    {
      float4 aA = ep[0], aB = ep[1], bA = ep[4], bB = ep[5];
      float4 cA = ep[8], cB = ep[9], dA = ep[12], dB = ep[13];
      FOLD8(f00, f10, aA, aB, 0)
      FOLD8(f01, f11, bA, bB, 0)
      FOLD8(f02, f12, cA, cB, 0)
      FOLD8(f03, f13, dA, dB, 0)
    }
    {
      float4 aA = ep[2], aB = ep[3], bA = ep[6], bB = ep[7];
      float4 cA = ep[10], cB = ep[11], dA = ep[14], dB = ep[15];
      FOLD8(f00, f10, aA, aB, 8)
      FOLD8(f01, f11, bA, bB, 8)
      FOLD8(f02, f12, cA, cB, 8)
      FOLD8(f03, f13, dA, dB, 8)
    }
    float v0, v1;
    v0 = (a0 + bflo(q0) + f00) * w0; v1 = (a1 + bfhi(q0) + f10) * w0; STATACC(v0, v1)
    v0 = (a0 + bflo(q1) + f01) * w1; v1 = (a1 + bfhi(q1) + f11) * w1; STATACC(v0, v1)
    v0 = (a0 + bflo(q2) + f02) * w2; v1 = (a1 + bfhi(q2) + f12) * w2; STATACC(v0, v1)
    v0 = (a0 + bflo(q3) + f03) * w3; v1 = (a1 + bfhi(q3) + f13) * w3; STATACC(v0, v1)
  }
  for (; i < hi; ++i) {
    int s = srcs[i];
    unsigned int q = qB[(size_t)s * 64 + lane];
    float w = ews[i];
    const float4* ep = (const float4*)(eattrg + (size_t)i * 16);
    float4 aA = ep[0], aB = ep[1], cA = ep[2], cB = ep[3];
    float f0 = 0.f, f1 = 0.f;
    FOLD8(f0, f1, aA, aB, 0)
    FOLD8(f0, f1, cA, cB, 8)
    float v0 = (a0 + bflo(q) + f0) * w;
    float v1 = (a1 + bfhi(q) + f1) * w;
    STATACC(v0, v1)
  }

  if (half) {
    float* cb = comb[pairIdx][lane];
    cb[0] = s0a; cb[1] = s1a; cb[2] = sq0; cb[3] = sq1;
    cb[4] = mn0; cb[5] = mn1; cb[6] = mx0; cb[7] = mx1;
  }
  __syncthreads();
  if (valid && !half) {
    const float* cb = comb[pairIdx][lane];
    s0a += cb[0]; s1a += cb[1]; sq0 += cb[2]; sq1 += cb[3];
    mn0 = fminf(mn0, cb[4]); mn1 = fminf(mn1, cb[5]);
    mx0 = fmaxf(mx0, cb[6]); mx1 = fmaxf(mx1, cb[7]);
    if (dg == 0) { mn0 = 0.f; mx0 = 0.f; mn1 = 0.f; mx1 = 0.f; }
    float inv = 1.f / (float)(dg > 0 ? dg : 1);
    float mean0 = s0a * inv, mean1 = s1a * inv;
    float sd0 = sqrtf(fmaxf(sq0 * inv - mean0 * mean0, 0.f) + kEps);
    float sd1 = sqrtf(fmaxf(sq1 * inv - mean1 * mean1, 0.f) + kEps);
    unsigned int* sp = stats + (size_t)n * 256;
    sp[0 * 64 + lane] = packbf(mean0, mean1);
    sp[1 * 64 + lane] = packbf(mn0, mn1);
    sp[2 * 64 + lane] = packbf(mx0, mx1);
    sp[3 * 64 + lane] = packbf(sd0, sd1);
  }
}

// ---------------- per-layer: post_nn + lin + BN partials ----------------
// Weight triplets {wm,wa,wt} packed per (j-pair, col) -> one b128 LDS read/iter.
__global__ __launch_bounds__(256) void post_kernel(
    const float* __restrict__ h, const unsigned int* __restrict__ stats,
    const int* __restrict__ coff, const float* __restrict__ adl,
    const float* __restrict__ postW, const float* __restrict__ postB,
    const float* __restrict__ linW, const float* __restrict__ linB,
    float* __restrict__ pre, float* __restrict__ bn, int N) {
  __shared__ unsigned int ph[512];         // h-block weight pairs: 2 KB
  __shared__ uint4 pq[2048];               // {wm,wa,wt,0} per (j-pair, col): 32 KB
  __shared__ unsigned int stu[4][256];     // per-wave raw stats rows: 4 KB
  __shared__ float red[8][32];             // BN partial reduce: 1 KB
  int tid = threadIdx.x;
  for (int i = tid; i < 512; i += 256) {
    int r = i >> 5, cc = i & 31, tP = cc >> 3, gq = cc & 7;
    ph[i] = packbf(postW[tP * 3328 + (2 * r) * 8 + gq],
                   postW[tP * 3328 + (2 * r + 1) * 8 + gq]);
  }
  for (int i = tid; i < 2048; i += 256) {
    int rr = i >> 5, cc = i & 31, tP = cc >> 3, gq = cc & 7;
    int stat = rr >> 4, jp = rr & 15;
    int fb = 32 + stat * 32 + 2 * jp;
    uint4 w;
    w.x = packbf(postW[tP * 3328 + fb * 8 + gq], postW[tP * 3328 + (fb + 1) * 8 + gq]);
    w.y = packbf(postW[tP * 3328 + (fb + 128) * 8 + gq], postW[tP * 3328 + (fb + 129) * 8 + gq]);
    w.z = packbf(postW[tP * 3328 + (fb + 256) * 8 + gq], postW[tP * 3328 + (fb + 257) * 8 + gq]);
    w.w = 0u;
    pq[i] = w;
  }
  __syncthreads();

  int wave = tid >> 6, lane = tid & 63;
  int c = lane & 31, hh = lane >> 5;
  int tP = c >> 3;
  float adN = adl[0];
  float bs = 0.f, bq = 0.f;

  for (int n = blockIdx.x * 4 + wave; n < N; n += gridDim.x * 4) {
    {
      uint4 su = ((const uint4*)stats)[(size_t)n * 64 + lane];
      ((uint4*)stu[wave])[lane] = su;   // per-wave region: no block barrier needed
    }
    int dg = coff[n + 1] - coff[n];
    float degc = (float)(dg > 0 ? dg : 1);
    float ad = adN / (float)N;
    float ld = logf(degc + 1.f);
    float amp = ld / ad, att = ad / ld;

    float acc = (hh == 0) ? postB[tP * 8 + (c & 7)] : 0.f;
    const float4* h4 = (const float4*)(h + (size_t)n * 32);
#pragma unroll
    for (int q4 = 0; q4 < 4; q4++) {
      float4 hv = h4[hh * 4 + q4];
      int r0 = hh * 8 + q4 * 2;
      unsigned int u0 = ph[r0 * 32 + c], u1 = ph[(r0 + 1) * 32 + c];
      acc = fmaf(hv.x, bflo(u0), acc);
      acc = fmaf(hv.y, bfhi(u0), acc);
      acc = fmaf(hv.z, bflo(u1), acc);
      acc = fmaf(hv.w, bfhi(u1), acc);
    }
#pragma unroll 8
    for (int jj = 0; jj < 32; jj++) {
      int sIdx = hh * 2 + (jj >> 4);
      int jp = jj & 15;
      unsigned int sv = stu[wave][sIdx * 64 + tP * 16 + jp];
      float v0 = bflo(sv), v1 = bfhi(sv);
      uint4 wq = pq[(sIdx * 16 + jp) * 32 + c];
      float w0 = bflo(wq.x); w0 = fmaf(amp, bflo(wq.y), w0); w0 = fmaf(att, bflo(wq.z), w0);
      float w1 = bfhi(wq.x); w1 = fmaf(amp, bfhi(wq.y), w1); w1 = fmaf(att, bfhi(wq.z), w1);
      acc = fmaf(v0, w0, acc);
      acc = fmaf(v1, w1, acc);
    }
    acc += __shfl_xor(acc, 32);
    float o = linB[c];
#pragma unroll
    for (int k = 0; k < 32; k++) {
      float a = __shfl(acc, k);
      o = fmaf(a, linW[k * 32 + c], o);
    }
    if (lane < 32) {
      pre[(size_t)n * 32 + c] = o;
      bs += o;
      bq = fmaf(o, o, bq);
    }
  }

  __syncthreads();
  if (lane < 32) {
    red[wave * 2 + 0][c] = bs;
    red[wave * 2 + 1][c] = bq;
  }
  __syncthreads();
  if (tid < 64) {
    int which = tid >> 5, cc = tid & 31;
    float s = red[0 * 2 + which][cc] + red[1 * 2 + which][cc] +
              red[2 * 2 + which][cc] + red[3 * 2 + which][cc];
    atomicAdd(&bn[which * 32 + cc], s);
  }
}

// ---------------- fused BN-apply + pooling, then MLP ----------------

__device__ __forceinline__ int lower_bound_dev(const int* a, int n, int key) {
  int lo = 0, hi = n;
  while (lo < hi) {
    int m = (lo + hi) >> 1;
    if (a[m] < key) lo = m + 1; else hi = m;
  }
  return lo;
}

__global__ void pool2_kernel(const float* __restrict__ pre, const float* __restrict__ bnv,
                             const float* __restrict__ gamma, const float* __restrict__ beta,
                             const int* __restrict__ batch, float* __restrict__ gp, int N) {
  int gi = blockIdx.x;  // 64 graphs
  int lo = lower_bound_dev(batch, N, gi);
  int hi = lower_bound_dev(batch, N, gi + 1);
  __shared__ float part[8][32];
  int j = threadIdx.x & 31, ch = threadIdx.x >> 5;
  float invN = 1.f / (float)N;
  float mu = bnv[j] * invN;
  float var = bnv[32 + j] * invN - mu * mu;
  float is = rsqrtf(var + kEps);
  float gm = gamma[j], bt = beta[j];
  float s = 0.f;
  for (int n = lo + ch; n < hi; n += 8)
    s += fmaxf((pre[(size_t)n * 32 + j] - mu) * is * gm + bt, 0.f);
  part[ch][j] = s;
  __syncthreads();
  if (threadIdx.x < 32) {
    float t = 0.f;
    for (int c2 = 0; c2 < 8; c2++) t += part[c2][j];
    gp[gi * 32 + j] = t;
  }
}

__global__ void mlp_kernel(const float* __restrict__ gp,
                           const float* __restrict__ W1, const float* __restrict__ b1,
                           const float* __restrict__ W2, const float* __restrict__ b2,
                           const float* __restrict__ W3, const float* __restrict__ b3,
                           float* __restrict__ out) {
  __shared__ float g1[64 * 32];
  __shared__ float g2[64 * 16];
  int tid = threadIdx.x;  // 256
  for (int i = tid; i < 2048; i += 256) {
    int r = i >> 5, c = i & 31;
    float s = b1[c];
    for (int k = 0; k < 32; k++) s += gp[r * 32 + k] * W1[k * 32 + c];
    g1[i] = fmaxf(s, 0.f);
  }
  __syncthreads();
  for (int i = tid; i < 1024; i += 256) {
    int r = i >> 4, c = i & 15;
    float s = b2[c];
    for (int k = 0; k < 32; k++) s += g1[r * 32 + k] * W2[k * 16 + c];
    g2[i] = fmaxf(s, 0.f);
  }
  __syncthreads();
  if (tid < 64) {
    float s = b3[0];
    for (int k = 0; k < 16; k++) s += g2[tid * 16 + k] * W3[k];
    out[tid] = s;
  }
}

// ---------------- launch ----------------

extern "C" void kernel_launch(void* const* d_in, const int* in_sizes, int n_in,
                              void* d_out, int out_size, void* d_ws, size_t ws_size,
                              hipStream_t stream) {
  (void)n_in; (void)out_size; (void)ws_size;
  const float* x     = (const float*)d_in[0];
  const float* eattr = (const float*)d_in[1];
  const float* ew    = (const float*)d_in[2];
  const int*   eidx  = (const int*)d_in[3];
  const int*   batch = (const int*)d_in[4];
  const float* nodeW = (const float*)d_in[5];
  const float* nodeB = (const float*)d_in[6];
  const float* edgeW = (const float*)d_in[7];
  const float* edgeB = (const float*)d_in[8];
  const float* encW  = (const float*)d_in[9];
  const float* encB  = (const float*)d_in[10];
  const float* preW  = (const float*)d_in[11];
  const float* preB  = (const float*)d_in[12];
  const float* postW = (const float*)d_in[13];
  const float* postB = (const float*)d_in[14];
  const float* linW  = (const float*)d_in[15];
  const float* linB  = (const float*)d_in[16];
  const float* bnG   = (const float*)d_in[17];
  const float* bnB   = (const float*)d_in[18];
  const float* W1    = (const float*)d_in[19];
  const float* b1    = (const float*)d_in[20];
  const float* W2    = (const float*)d_in[21];
  const float* b2    = (const float*)d_in[22];
  const float* W3    = (const float*)d_in[23];
  const float* b3    = (const float*)d_in[24];
  float* out = (float*)d_out;

  int N = in_sizes[0] / 128;
  int E = in_sizes[2];
  const int* srcp = eidx;
  const int* dstp = eidx + E;

  char* wsb = (char*)d_ws;
  size_t woff = 0;
  auto alloc = [&](size_t bytes) -> void* {
    void* p = (void*)(wsb + woff);
    woff += (bytes + 255) & ~(size_t)255;
    return p;
  };
  int* deg   = (int*)alloc((size_t)N * 4);
  int* cnt   = (int*)alloc((size_t)N * 4);
  int* coff  = (int*)alloc((size_t)(N + 1) * 4);
  int* part  = (int*)alloc(64 * 4);
  int* srcs  = (int*)alloc((size_t)E * 4);
  float* ews = (float*)alloc((size_t)E * 4);
  float* eattrg = (float*)alloc((size_t)E * 16 * 4);
  float* h    = (float*)alloc((size_t)N * 32 * 4);
  float* pre  = (float*)alloc((size_t)N * 32 * 4);
  float* adl  = (float*)alloc(256);
  float* bnbuf = (float*)alloc(2 * 64 * 4);
  float* gp   = (float*)alloc(64 * 32 * 4);
  float* WfB  = (float*)alloc(2 * 4 * 16 * 32 * 4);
  float* bfB  = (float*)alloc(2 * 4 * 32 * 4);
  unsigned short* qB  = (unsigned short*)alloc((size_t)N * 128 * 2);
  unsigned short* AB  = (unsigned short*)alloc((size_t)N * 128 * 2);
  unsigned int* stats = (unsigned int*)alloc((size_t)N * 256 * 4);

  int nb = (N + 1023) / 1024;
  zero_kernel<<<(N + 255) / 256, 256, 0, stream>>>(deg, cnt, bnbuf, N);
  hist_kernel<<<(E + 255) / 256, 256, 0, stream>>>(dstp, deg, E);
  scan1_kernel<<<nb, 1024, 0, stream>>>(deg, coff, part, N);
  scan2_kernel<<<1, 64, 0, stream>>>(part, coff, nb, N);
  scan3_kernel<<<nb, 1024, 0, stream>>>(coff, part, N);
  fill_kernel<<<(E + 255) / 256, 256, 0, stream>>>(srcp, dstp, ew, (const float4*)eattr,
                                                   coff, cnt, srcs, ews, (float4*)eattrg, E);
  adl_kernel<<<1, 1024, 0, stream>>>(deg, adl, N);
  node_emb_kernel<<<(N + 7) / 8, 256, 0, stream>>>(x, nodeW, nodeB, h, N);
  fuse_kernel<<<1, 256, 0, stream>>>(edgeW, edgeB, encW, encB, preW, preB, WfB, bfB);

  int grid_a = (N + 1) / 2;   // 2 nodes per block, 2 waves per node

  // layer 0
  prep_kernel<<<(N + 15) / 16, 256, 0, stream>>>(h, preW, bfB, qB, AB, N);
  agg6_kernel<<<grid_a, 256, 0, stream>>>(
      (const unsigned int*)qB, (const unsigned int*)AB, coff, srcs, ews,
      eattrg, WfB, stats, N);
  post_kernel<<<1280, 256, 0, stream>>>(
      h, stats, coff, adl, postW, postB, linW, linB, pre, bnbuf, N);
  // fused bn_apply(l0) + prep(l1)
  bnprep_kernel<<<(N + 15) / 16, 256, 0, stream>>>(
      pre, bnbuf, bnG, bnB, preW + 12288, bfB + 128, h, qB, AB, N);
  // layer 1
  agg6_kernel<<<grid_a, 256, 0, stream>>>(
      (const unsigned int*)qB, (const unsigned int*)AB, coff, srcs, ews,
      eattrg, WfB + 2048, stats, N);
  post_kernel<<<1280, 256, 0, stream>>>(
      h, stats, coff, adl, postW + 13312, postB + 32, linW + 1024, linB + 32,
      pre, bnbuf + 64, N);
  // fused bn_apply(l1) + pooling
  pool2_kernel<<<64, 256, 0, stream>>>(pre, bnbuf + 64, bnG + 32, bnB + 32, batch, gp, N);
  mlp_kernel<<<1, 256, 0, stream>>>(gp, W1, b1, W2, b2, W3, b3, out);
}